// Round 1
// baseline (5020.038 us; speedup 1.0000x reference)
//
#include <hip/hip_runtime.h>
#include <hip/hip_bf16.h>
#include <math.h>

// Problem constants
constexpr int S    = 2048;
constexpr int D    = 1024;
constexpr int NH   = 16;
constexpr int HD   = 64;
constexpr int RD   = 32;
constexpr int KVC  = 256;
constexpr int QC   = 384;
constexpr int H2   = 32;      // 2*NH half-heads
constexpr int QKD  = 48;      // HD/2 + RD/2
constexpr float SCALE    = 0.14433756729740643f;  // 48^-0.5
constexpr float LAM_INIT = 0.2f;                  // 0.8 - 0.6*exp(0)
constexpr float EPS      = 1e-5f;

// ---------------------------------------------------------------- GEMM (f32)
// C[M,N] = A[M,K] @ B[K,N].  64x64 tile, BK=16, 256 threads, 4x4 per thread.
__global__ __launch_bounds__(256) void gemm_f32(
    const float* __restrict__ A, const float* __restrict__ B,
    float* __restrict__ C, int M, int K, int N) {
  __shared__ float As[16][64];
  __shared__ float Bs[16][64];
  const int tid = threadIdx.x;
  const int m0 = blockIdx.y * 64, n0 = blockIdx.x * 64;
  const int ty = tid >> 4, tx = tid & 15;
  float acc[4][4] = {};
  for (int k0 = 0; k0 < K; k0 += 16) {
#pragma unroll
    for (int r = 0; r < 4; ++r) {
      int i = tid + r * 256;
      int am = i >> 4, ak = i & 15;
      int gm = m0 + am, gk = k0 + ak;
      As[ak][am] = (gm < M && gk < K) ? A[(size_t)gm * K + gk] : 0.f;
    }
#pragma unroll
    for (int r = 0; r < 4; ++r) {
      int i = tid + r * 256;
      int bk = i >> 6, bn = i & 63;
      int gk = k0 + bk, gn = n0 + bn;
      Bs[bk][bn] = (gk < K && gn < N) ? B[(size_t)gk * N + gn] : 0.f;
    }
    __syncthreads();
#pragma unroll
    for (int kk = 0; kk < 16; ++kk) {
      float av[4], bv[4];
#pragma unroll
      for (int r = 0; r < 4; ++r) av[r] = As[kk][ty * 4 + r];
#pragma unroll
      for (int cidx = 0; cidx < 4; ++cidx) bv[cidx] = Bs[kk][tx * 4 + cidx];
#pragma unroll
      for (int r = 0; r < 4; ++r)
#pragma unroll
        for (int cidx = 0; cidx < 4; ++cidx) acc[r][cidx] += av[r] * bv[cidx];
    }
    __syncthreads();
  }
  for (int r = 0; r < 4; ++r) {
    int gm = m0 + ty * 4 + r;
    if (gm >= M) continue;
    for (int cidx = 0; cidx < 4; ++cidx) {
      int gn = n0 + tx * 4 + cidx;
      if (gn < N) C[(size_t)gm * N + gn] = acc[r][cidx];
    }
  }
}

// ------------------------------------------------------------ row rmsnorm
__global__ __launch_bounds__(256) void rmsnorm_rows(
    const float* __restrict__ in, const float* __restrict__ w,
    float* __restrict__ out, int stride_in, int width) {
  const int row = blockIdx.x;
  const float* x = in + (size_t)row * stride_in;
  float ss = 0.f;
  for (int j = threadIdx.x; j < width; j += 256) { float v = x[j]; ss += v * v; }
  __shared__ float red[256];
  red[threadIdx.x] = ss;
  __syncthreads();
  for (int o = 128; o; o >>= 1) {
    if (threadIdx.x < o) red[threadIdx.x] += red[threadIdx.x + o];
    __syncthreads();
  }
  const float sc = rsqrtf(red[0] / (float)width + EPS);
  for (int j = threadIdx.x; j < width; j += 256)
    out[(size_t)row * width + j] = x[j] * sc * w[j];
}

// ------------------------------------------- assemble q_f^T, k_f^T with RoPE
// qfT/kfT layout: [h2][48][S]
__global__ __launch_bounds__(64) void assemble_qk(
    const float* __restrict__ qp, const float* __restrict__ kv,
    const float* __restrict__ c, const float* __restrict__ freqs,
    float* __restrict__ qfT, float* __restrict__ kfT) {
  const int h2 = blockIdx.x;
  const int s = blockIdx.y * 64 + threadIdx.x;
  const int m = h2 >> 1, e = h2 & 1;
  const int sp = s >> 2;  // s = sp*NSEQ + ns, NSEQ=4
  float cs[8], sn[8];
  if (sp > 0) {
#pragma unroll
    for (int t = 0; t < 8; ++t) {
      float a = freqs[(sp - 1) * 8 + t];
      cs[t] = cosf(a); sn[t] = sinf(a);
    }
  }
  // ---- q
  const float* qrow = qp + (size_t)s * (NH * (HD + RD)) + m * (HD + RD);
#pragma unroll
  for (int j = 0; j < 32; ++j)
    qfT[((size_t)(h2 * QKD + j)) * S + s] = qrow[e * 32 + j];
  float r[16];
#pragma unroll
  for (int j = 0; j < 16; ++j) r[j] = qrow[HD + e * 16 + j];
  if (sp > 0) {
#pragma unroll
    for (int t = 0; t < 8; ++t) {
      float a = r[2 * t], b = r[2 * t + 1];
      r[2 * t]     = a * cs[t] - b * sn[t];
      r[2 * t + 1] = a * sn[t] + b * cs[t];
    }
  }
#pragma unroll
  for (int j = 0; j < 16; ++j)
    qfT[((size_t)(h2 * QKD + 32 + j)) * S + s] = r[j];
  // ---- k
  const float* krow = kv + (size_t)s * (NH * 2 * HD) + m * (2 * HD);
#pragma unroll
  for (int j = 0; j < 32; ++j)
    kfT[((size_t)(h2 * QKD + j)) * S + s] = krow[e * 32 + j];
#pragma unroll
  for (int j = 0; j < 16; ++j)
    r[j] = c[(size_t)s * (KVC + RD) + KVC + e * 16 + j];
  if (sp > 0) {
#pragma unroll
    for (int t = 0; t < 8; ++t) {
      float a = r[2 * t], b = r[2 * t + 1];
      r[2 * t]     = a * cs[t] - b * sn[t];
      r[2 * t + 1] = a * sn[t] + b * cs[t];
    }
  }
#pragma unroll
  for (int j = 0; j < 16; ++j)
    kfT[((size_t)(h2 * QKD + 32 + j)) * S + s] = r[j];
}

// v layout [h][S][64]
__global__ __launch_bounds__(256) void assemble_v(
    const float* __restrict__ kv, float* __restrict__ vv) {
  const int i = blockIdx.x * 256 + threadIdx.x;  // < 16*2048*64
  const int dd = i & 63;
  const int s = (i >> 6) & (S - 1);
  const int h = i >> 17;
  vv[i] = kv[(size_t)s * (NH * 2 * HD) + h * (2 * HD) + HD + dd];
}

// lam scalar
__global__ __launch_bounds__(64) void compute_lam(
    const float* __restrict__ lk1, const float* __restrict__ lk2,
    const float* __restrict__ lq1, const float* __restrict__ lq2,
    float* __restrict__ lam) {
  const int t = threadIdx.x;
  float p1 = (t < 32) ? lk1[t] * lq1[t] : 0.f;
  float p2 = (t < 32) ? lk2[t] * lq2[t] : 0.f;
  for (int o = 16; o; o >>= 1) {
    p1 += __shfl_down(p1, o);
    p2 += __shfl_down(p2, o);
  }
  if (t == 0) *lam = expf(p1) - expf(p2) + LAM_INIT;
}

// ------------------------------------------ Pass A: per-row max + 1/denom
__global__ __launch_bounds__(256) void attn_md(
    const float* __restrict__ qfT, const float* __restrict__ kfT,
    float* __restrict__ mOut, float* __restrict__ rdOut) {
  const int q = blockIdx.x, h2 = blockIdx.y;
  __shared__ float qv[QKD];
  if (threadIdx.x < QKD)
    qv[threadIdx.x] = qfT[((size_t)(h2 * QKD + threadIdx.x)) * S + q];
  __syncthreads();
  float mloc = -1e30f, dloc = 0.f;
  for (int k = threadIdx.x; k <= q; k += 256) {
    float sdot = 0.f;
#pragma unroll
    for (int j = 0; j < QKD; ++j)
      sdot += qv[j] * kfT[((size_t)(h2 * QKD + j)) * S + k];
    float av = fabsf(sdot * SCALE);
    float nm = fmaxf(mloc, av);
    dloc = dloc * expf(mloc - nm) + expf(av - nm);
    mloc = nm;
  }
  __shared__ float sm[256], sd[256];
  sm[threadIdx.x] = mloc; sd[threadIdx.x] = dloc;
  __syncthreads();
  for (int o = 128; o; o >>= 1) {
    if (threadIdx.x < o) {
      float m1 = sm[threadIdx.x], d1 = sd[threadIdx.x];
      float m2 = sm[threadIdx.x + o], d2 = sd[threadIdx.x + o];
      float nm = fmaxf(m1, m2);
      sm[threadIdx.x] = nm;
      sd[threadIdx.x] = d1 * expf(m1 - nm) + d2 * expf(m2 - nm);
    }
    __syncthreads();
  }
  if (threadIdx.x == 0) {
    mOut[h2 * S + q] = sm[0];
    rdOut[h2 * S + q] = 1.0f / sd[0];
  }
}

// ------------------------------------------ Pass B: g[h][k] = mean_q p1[q,k]
__global__ __launch_bounds__(256) void attn_g(
    const float* __restrict__ qfT, const float* __restrict__ kfT,
    const float* __restrict__ mIn, const float* __restrict__ rdIn,
    float* __restrict__ g) {
  const int k = blockIdx.x, h = blockIdx.y, h2 = 2 * h;
  __shared__ float kvv[QKD];
  if (threadIdx.x < QKD)
    kvv[threadIdx.x] = kfT[((size_t)(h2 * QKD + threadIdx.x)) * S + k];
  __syncthreads();
  float acc = 0.f;
  for (int q = k + threadIdx.x; q < S; q += 256) {
    float sdot = 0.f;
#pragma unroll
    for (int j = 0; j < QKD; ++j)
      sdot += kvv[j] * qfT[((size_t)(h2 * QKD + j)) * S + q];
    sdot *= SCALE;
    float av = fabsf(sdot);
    float sg = (sdot > 0.f) ? 1.f : ((sdot < 0.f) ? -1.f : 0.f);
    acc += sg * expf(av - mIn[h2 * S + q]) * rdIn[h2 * S + q];
  }
  __shared__ float red[256];
  red[threadIdx.x] = acc;
  __syncthreads();
  for (int o = 128; o; o >>= 1) {
    if (threadIdx.x < o) red[threadIdx.x] += red[threadIdx.x + o];
    __syncthreads();
  }
  if (threadIdx.x == 0) g[h * S + k] = red[0] * (1.0f / (float)S);
}

// --------------------------- Pass C: prefix sum over k of g[h,k]*v[h,k,dd]
__global__ __launch_bounds__(64) void attn_gvc(
    const float* __restrict__ g, const float* __restrict__ vv,
    float* __restrict__ gvc) {
  const int h = blockIdx.x, dd = threadIdx.x;
  float run = 0.f;
#pragma unroll 4
  for (int k = 0; k < S; ++k) {
    run += g[h * S + k] * vv[((size_t)(h * S + k)) * 64 + dd];
    gvc[((size_t)(h * S + k)) * 64 + dd] = run;
  }
}

// --------------- Pass D: out = (p1 - lam*p2)@V + lam*gvc ; fused rmsnorm
__global__ __launch_bounds__(256) void attn_out(
    const float* __restrict__ qfT, const float* __restrict__ kfT,
    const float* __restrict__ vv, const float* __restrict__ mIn,
    const float* __restrict__ rdIn, const float* __restrict__ gvc,
    const float* __restrict__ lamPtr, const float* __restrict__ normW,
    float* __restrict__ normed) {
  const int q = blockIdx.x, h = blockIdx.y;
  const int h2a = 2 * h, h2b = 2 * h + 1;
  __shared__ float qv1[QKD], qv2[QKD], pl[256], red[256];
  const int tid = threadIdx.x;
  if (tid < QKD) qv1[tid] = qfT[((size_t)(h2a * QKD + tid)) * S + q];
  else if (tid >= 64 && tid < 64 + QKD)
    qv2[tid - 64] = qfT[((size_t)(h2b * QKD + (tid - 64))) * S + q];
  __syncthreads();
  const float m1 = mIn[h2a * S + q], rd1 = rdIn[h2a * S + q];
  const float m2 = mIn[h2b * S + q], rd2 = rdIn[h2b * S + q];
  const float lam = *lamPtr;
  const int gg = tid >> 6, dd = tid & 63;
  float acc = 0.f;
  for (int k0 = 0; k0 <= q; k0 += 256) {
    const int k = k0 + tid;
    float p = 0.f;
    if (k <= q) {
      float s1 = 0.f, s2 = 0.f;
#pragma unroll
      for (int j = 0; j < QKD; ++j)
        s1 += qv1[j] * kfT[((size_t)(h2a * QKD + j)) * S + k];
#pragma unroll
      for (int j = 0; j < QKD; ++j)
        s2 += qv2[j] * kfT[((size_t)(h2b * QKD + j)) * S + k];
      s1 *= SCALE; s2 *= SCALE;
      float sg1 = (s1 > 0.f) ? 1.f : ((s1 < 0.f) ? -1.f : 0.f);
      float sg2 = (s2 > 0.f) ? 1.f : ((s2 < 0.f) ? -1.f : 0.f);
      p = sg1 * expf(fabsf(s1) - m1) * rd1
        - lam * (sg2 * expf(fabsf(s2) - m2) * rd2);
    }
    pl[tid] = p;
    __syncthreads();
    const int lim = min(255, q - k0);
    const int hi = min(gg * 64 + 63, lim);
    for (int idx = gg * 64; idx <= hi; ++idx)
      acc += pl[idx] * vv[((size_t)(h * S + k0 + idx)) * 64 + dd];
    __syncthreads();
  }
  red[tid] = acc;
  __syncthreads();
  if (gg == 0) {
    float val = red[dd] + red[64 + dd] + red[128 + dd] + red[192 + dd];
    val += lam * gvc[((size_t)(h * S + q)) * 64 + dd];
    float ss = val * val;
#pragma unroll
    for (int o = 32; o; o >>= 1) ss += __shfl_xor(ss, o);
    float sc = rsqrtf(ss * (1.0f / 64.0f) + EPS);
    normed[(size_t)q * D + h * 64 + dd] = val * sc * normW[dd];
  }
}

// ----------------------------------------------------------------- launch
extern "C" void kernel_launch(void* const* d_in, const int* in_sizes, int n_in,
                              void* d_out, int out_size, void* d_ws, size_t ws_size,
                              hipStream_t stream) {
  const float* x     = (const float*)d_in[0];
  // d_in[1] = mask (causal triu, recomputed implicitly)
  const float* freqs = (const float*)d_in[2];
  const float* Wkvd  = (const float*)d_in[3];
  const float* Wqd   = (const float*)d_in[4];
  const float* kvnw  = (const float*)d_in[5];
  const float* qnw   = (const float*)d_in[6];
  const float* Wkvup = (const float*)d_in[7];
  const float* Wqup  = (const float*)d_in[8];
  const float* lk1   = (const float*)d_in[9];
  const float* lk2   = (const float*)d_in[10];
  const float* lq1   = (const float*)d_in[11];
  const float* lq2   = (const float*)d_in[12];
  const float* normw = (const float*)d_in[13];
  const float* Wo    = (const float*)d_in[14];
  float* out = (float*)d_out;

  float* ws = (float*)d_ws;
  float* c      = ws;                       // S*288
  float* ckv    = c    + (size_t)S * 288;   // S*256
  float* cqr    = ckv  + (size_t)S * 256;   // S*384
  float* cq     = cqr  + (size_t)S * 384;   // S*384
  float* kvbuf  = cq   + (size_t)S * 384;   // S*2048
  float* qp     = kvbuf+ (size_t)S * 2048;  // S*1536
  float* qfT    = qp   + (size_t)S * 1536;  // 32*48*S
  float* kfT    = qfT  + (size_t)H2 * QKD * S;  // 32*48*S
  float* vv     = kfT  + (size_t)H2 * QKD * S;  // 16*S*64
  float* mbuf   = vv   + (size_t)NH * S * 64;   // 32*S
  float* rdbuf  = mbuf + (size_t)H2 * S;    // 32*S
  float* gbuf   = rdbuf+ (size_t)H2 * S;    // 16*S
  float* gvc    = gbuf + (size_t)NH * S;    // 16*S*64
  float* normed = gvc  + (size_t)NH * S * 64;   // S*1024
  float* lam    = normed + (size_t)S * D;   // 1

  // 1. down-projections
  gemm_f32<<<dim3((288 + 63) / 64, S / 64), 256, 0, stream>>>(x, Wkvd, c, S, D, 288);
  gemm_f32<<<dim3((384 + 63) / 64, S / 64), 256, 0, stream>>>(x, Wqd, cqr, S, D, 384);
  // 2. rmsnorms
  rmsnorm_rows<<<S, 256, 0, stream>>>(c, kvnw, ckv, 288, 256);
  rmsnorm_rows<<<S, 256, 0, stream>>>(cqr, qnw, cq, 384, 384);
  // 3. up-projections
  gemm_f32<<<dim3(2048 / 64, S / 64), 256, 0, stream>>>(ckv, Wkvup, kvbuf, S, 256, 2048);
  gemm_f32<<<dim3(1536 / 64, S / 64), 256, 0, stream>>>(cq, Wqup, qp, S, 384, 1536);
  // 4. assemble heads with RoPE
  assemble_qk<<<dim3(H2, S / 64), 64, 0, stream>>>(qp, kvbuf, c, freqs, qfT, kfT);
  assemble_v<<<(NH * S * 64) / 256, 256, 0, stream>>>(kvbuf, vv);
  compute_lam<<<1, 64, 0, stream>>>(lk1, lk2, lq1, lq2, lam);
  // 5. attention passes
  attn_md<<<dim3(S, H2), 256, 0, stream>>>(qfT, kfT, mbuf, rdbuf);
  attn_g<<<dim3(S, NH), 256, 0, stream>>>(qfT, kfT, mbuf, rdbuf, gbuf);
  attn_gvc<<<NH, 64, 0, stream>>>(gbuf, vv, gvc);
  attn_out<<<dim3(S, NH), 256, 0, stream>>>(qfT, kfT, vv, mbuf, rdbuf, gvc, lam, normw, normed);
  // 6. output projection
  gemm_f32<<<dim3(1024 / 64, S / 64), 256, 0, stream>>>(normed, Wo, out, S, D, D);
}